// Round 12
// baseline (127.583 us; speedup 1.0000x reference)
//
#include <hip/hip_runtime.h>

// ---------------------------------------------------------------------------
// CVX_Reasoning_Engine — Round 12: deeper ring (16) + 64-row blocks.
//   R11's asm vmcnt ring broke the serialization (fused ~37 us). Residuals:
//   depth 8 < latency/issue ratio, and 483 MB chip L2 weight traffic.
//   (a) DEP 16 on big layers; (b) 64 rows/block, 8 waves 2m x 4n: m-twin
//   waves stream identical W addresses -> L1 dedup halves L2 traffic.
//   Per-wave stream identical to R11. Grid 256, LDS 137 KB, 1 block/CU.
// ---------------------------------------------------------------------------

#define MROWS 16384

typedef __attribute__((ext_vector_type(8))) short bf16x8;   // 8 bf16 = 4 VGPRs
typedef __attribute__((ext_vector_type(4))) float floatx4;

__device__ __forceinline__ unsigned short f2bf(float x) {
    union { float f; unsigned u; } c; c.f = x;
    unsigned r = c.u + 0x7fffu + ((c.u >> 16) & 1u);   // RNE
    return (unsigned short)(r >> 16);
}
__device__ __forceinline__ float bf2f(unsigned short b) {
    union { unsigned u; float f; } c; c.u = ((unsigned)b) << 16;
    return c.f;
}

// --- invisible-to-compiler 16B global load (1 KB/wave) ----------------------
__device__ __forceinline__ bf16x8 gload(const unsigned short* p) {
    bf16x8 r;
    asm volatile("global_load_dwordx4 %0, %1, off"
                 : "=&v"(r)
                 : "v"((unsigned long long)(size_t)p)
                 : "memory");
    return r;
}
template<int IMM>
__device__ __forceinline__ void vwait(bf16x8& v) {
    asm volatile("s_waitcnt vmcnt(%1)" : "+v"(v) : "n"(IMM) : "memory");
}
__device__ __forceinline__ void drain4(bf16x8 (&r)[4]) {
    asm volatile("s_waitcnt vmcnt(0)"
                 : "+v"(r[0]), "+v"(r[1]), "+v"(r[2]), "+v"(r[3]) :: "memory");
}
__device__ __forceinline__ void drain16(bf16x8 (&r)[16]) {
    asm volatile("s_waitcnt vmcnt(0)"
                 : "+v"(r[0]), "+v"(r[1]), "+v"(r[2]), "+v"(r[3]),
                   "+v"(r[4]), "+v"(r[5]), "+v"(r[6]), "+v"(r[7]),
                   "+v"(r[8]), "+v"(r[9]), "+v"(r[10]), "+v"(r[11]),
                   "+v"(r[12]), "+v"(r[13]), "+v"(r[14]), "+v"(r[15]) :: "memory");
}

// ---- pack weights -> ks-major fragment-ordered bf16 (R11 verbatim) ---------
__global__ __launch_bounds__(256) void pack_wt(
    const float* __restrict__ W1, unsigned short* __restrict__ T1,
    const float* __restrict__ W2, unsigned short* __restrict__ T2,
    const float* __restrict__ W3, unsigned short* __restrict__ T3,
    const float* __restrict__ W4, unsigned short* __restrict__ T4,
    const float* __restrict__ W5, unsigned short* __restrict__ T5)
{
    const int idx = blockIdx.x * 256 + threadIdx.x;
    if (blockIdx.y == 4) {            // W5: K=64, N=256 -> NT=16, KS=2, hi/lo
        if (idx >= 256 * 64) return;
        const int k = idx >> 8, n = idx & 255;
        const float v = W5[idx];
        const unsigned short hi = f2bf(v);
        const unsigned short lo = f2bf(v - bf2f(hi));
        const int ntile = n >> 4, m_l = n & 15;
        const int ks = k >> 5, quad = (k >> 3) & 3, e = k & 7;
        const size_t b = (size_t)(((ks * 16 + ntile) * 2) * 64 + quad * 16 + m_l) * 8 + e;
        T5[b] = hi; T5[b + 512] = lo;
        return;
    }
    const float* W; unsigned short* T; int Kreal, nshift;
    switch (blockIdx.y) {
        case 0:  W = W1; T = T1; Kreal = 516; nshift = 9; break;
        case 1:  W = W2; T = T2; Kreal = 512; nshift = 8; break;
        case 2:  W = W3; T = T3; Kreal = 256; nshift = 7; break;
        default: W = W4; T = T4; Kreal = 128; nshift = 6; break;
    }
    const int N = 1 << nshift, NT = N >> 4;
    const int KS = (Kreal + 31) >> 5;
    if (idx >= N * KS * 32) return;
    const int k = idx >> nshift;
    const int n = idx & (N - 1);
    const unsigned short v = (k < Kreal) ? f2bf(W[idx]) : (unsigned short)0;
    const int ntile = n >> 4, m_l = n & 15;
    const int ks = k >> 5, quad = (k >> 3) & 3, e = k & 7;
    T[(size_t)((ks * NT + ntile) * 64 + quad * 16 + m_l) * 8 + e] = v;
}

// ---- LDS layout (ushort elems), 64-row block --------------------------------
// A [0,35328): zs 64x552. After L1 dead: h2 64x264 @0 (L2 out).
//   After L3 dead: p fp32 64x260 @0 (= 33280 us).
// B [35328,68608): h1 64x520. After L2 dead: h3 64x136 @35328,
//   h4 64x72 @44032 (ends 48640).
// Total 68,608 us = 137,216 B -> 1 block/CU.
#define OFF_ZS   0
#define LD_ZS    552
#define OFF_H1   35328
#define LD_H1    520
#define OFF_H2   0
#define LD_H2    264
#define OFF_H3   35328
#define LD_H3    136
#define OFF_H4   44032
#define LD_H4    72
#define OFF_P    0
#define LD_P     260
#define LDS_TOT  68608

// streamed MFMA layer for wave (wm,wn): rows mrow..mrow+32, cols wn-slice.
template<int NF, int KSTEPS, int NT, int DEP>
__device__ __forceinline__ void layer_stream(
    unsigned short* lds, int offA, int lda, int offC, int ldc,
    const unsigned short* __restrict__ Wt,
    const float* __restrict__ bias, int wn, int mrow, int lane)
{
    const int m_l = lane & 15, quad = lane >> 4;
    constexpr int NFR = NF * KSTEPS;
    const unsigned short* __restrict__ Wb = Wt + ((size_t)(wn * NF) * 64 + lane) * 8;

    floatx4 acc[2][NF];
    #pragma unroll
    for (int j = 0; j < NF; ++j) {
        const float bv = bias[wn * (NF * 16) + j * 16 + m_l];
        acc[0][j] = (floatx4){bv, bv, bv, bv};
        acc[1][j] = (floatx4){bv, bv, bv, bv};
    }

    bf16x8 ring[DEP];
    #pragma unroll
    for (int f = 0; f < DEP; ++f) {
        const int g = (f < NFR) ? f : 0;
        ring[f] = gload(Wb + (size_t)((g / NF) * NT + (g % NF)) * 512);
    }
    bf16x8 a0, a1;
    #pragma unroll
    for (int f = 0; f < NFR; ++f) {
        const int ks = f / NF, j = f - ks * NF;
        if (j == 0) {
            a0 = *(const bf16x8*)&lds[offA + (mrow + m_l     ) * lda + ks*32 + quad*8];
            a1 = *(const bf16x8*)&lds[offA + (mrow + m_l + 16) * lda + ks*32 + quad*8];
        }
        vwait<DEP - 1>(ring[f % DEP]);
        acc[0][j] = __builtin_amdgcn_mfma_f32_16x16x32_bf16(a0, ring[f % DEP], acc[0][j], 0, 0, 0);
        acc[1][j] = __builtin_amdgcn_mfma_f32_16x16x32_bf16(a1, ring[f % DEP], acc[1][j], 0, 0, 0);
        const int nf2 = (f + DEP < NFR) ? f + DEP : 0;   // tail: dummy re-issues
        ring[f % DEP] = gload(Wb + (size_t)((nf2 / NF) * NT + (nf2 % NF)) * 512);
    }
    if constexpr (DEP == 16) drain16(ring); else drain4(ring);

    #pragma unroll
    for (int j = 0; j < NF; ++j) {
        const int col = wn * (NF * 16) + j * 16 + m_l;
        #pragma unroll
        for (int i = 0; i < 2; ++i)
            #pragma unroll
            for (int r = 0; r < 4; ++r) {
                float v = acc[i][j][r];
                v = v > 0.f ? v : 0.2f * v;
                lds[offC + (mrow + i*16 + quad*4 + r) * ldc + col] = f2bf(v);
            }
    }
}

__global__ __launch_bounds__(512, 2) void fused_mlp_qp(
    const float* __restrict__ z, const float* __restrict__ bounds,
    const unsigned short* __restrict__ Wt1, const float* __restrict__ c1,
    const unsigned short* __restrict__ Wt2, const float* __restrict__ c2,
    const unsigned short* __restrict__ Wt3, const float* __restrict__ c3,
    const unsigned short* __restrict__ Wt4, const float* __restrict__ c4,
    const unsigned short* __restrict__ Wt5, const float* __restrict__ c5,
    float* __restrict__ out)
{
    __shared__ unsigned short lds[LDS_TOT];
    const int tid  = threadIdx.x;
    const int wid  = tid >> 6, lane = tid & 63;    // wid 0..7
    const int wm   = wid >> 2, wn = wid & 3;       // 2m x 4n
    const int mrow = wm * 32;
    const int m_l  = lane & 15, quad = lane >> 4;
    const int bm   = blockIdx.x * 64;

    const float4 bnd = *(const float4*)bounds;

    // ---- stage ALL of z (one latency; barrier drains everything) -----------
    {
        const float4* __restrict__ zf = (const float4*)(z + (size_t)bm * 512);
        #pragma unroll
        for (int i = 0; i < 16; ++i) {
            const int f   = i * 512 + tid;          // float4 idx in 64x128
            const int row = f >> 7, c4i = f & 127;
            const float4 v = zf[f];
            unsigned short t4[4] = {f2bf(v.x), f2bf(v.y), f2bf(v.z), f2bf(v.w)};
            *(uint2*)&lds[OFF_ZS + row * LD_ZS + c4i * 4] = *(uint2*)t4;
        }
        if (tid < 320) {   // cols 512..551: bounds then zeros (5 chunks x 64 rows)
            const int row = tid / 5, j = tid % 5;
            unsigned short t8[8] = {0,0,0,0,0,0,0,0};
            if (j == 0) { t8[0] = f2bf(bnd.x); t8[1] = f2bf(bnd.y);
                          t8[2] = f2bf(bnd.z); t8[3] = f2bf(bnd.w); }
            *(uint4*)&lds[OFF_ZS + row * LD_ZS + 512 + j * 8] = *(uint4*)t8;
        }
    }
    __syncthreads();

    // ---- streamed MFMA layers 1-4 ------------------------------------------
    layer_stream<8,17,32,16>(lds, OFF_ZS, LD_ZS, OFF_H1, LD_H1, Wt1, c1, wn, mrow, lane);
    __syncthreads();
    layer_stream<4,16,16,16>(lds, OFF_H1, LD_H1, OFF_H2, LD_H2, Wt2, c2, wn, mrow, lane);
    __syncthreads();
    layer_stream<2,8, 8, 16>(lds, OFF_H2, LD_H2, OFF_H3, LD_H3, Wt3, c3, wn, mrow, lane);
    __syncthreads();
    layer_stream<1,4, 4, 4 >(lds, OFF_H3, LD_H3, OFF_H4, LD_H4, Wt4, c4, wn, mrow, lane);
    __syncthreads();

    // ---- Layer 5: split-bf16 W5 stream (NFR=16: ks(2) x j(4) x {hi,lo}) ----
    {
        const unsigned short* __restrict__ Wb5 = Wt5 + (size_t)wn * 4096 + (size_t)lane * 8;
        floatx4 acc[2][4];
        #pragma unroll
        for (int j = 0; j < 4; ++j) {
            const float bv = c5[wn * 64 + j * 16 + m_l];
            acc[0][j] = (floatx4){bv, bv, bv, bv};
            acc[1][j] = (floatx4){bv, bv, bv, bv};
        }
        auto w5off = [](int g) {   // g = ((ks*4 + j)*2 + hl) local to wave
            const int ks = g >> 3, rem = g & 7;
            return (size_t)ks * 16384 + (size_t)(rem >> 1) * 1024 + (size_t)(rem & 1) * 512;
        };
        bf16x8 ring[16];
        #pragma unroll
        for (int f = 0; f < 16; ++f) ring[f] = gload(Wb5 + w5off(f));
        bf16x8 a0, a1;
        #pragma unroll
        for (int f = 0; f < 16; ++f) {
            const int ks = f >> 3, rem = f & 7, j = rem >> 1;
            if (rem == 0) {
                a0 = *(const bf16x8*)&lds[OFF_H4 + (mrow + m_l     ) * LD_H4 + ks*32 + quad*8];
                a1 = *(const bf16x8*)&lds[OFF_H4 + (mrow + m_l + 16) * LD_H4 + ks*32 + quad*8];
            }
            vwait<15>(ring[f]);
            acc[0][j] = __builtin_amdgcn_mfma_f32_16x16x32_bf16(a0, ring[f], acc[0][j], 0, 0, 0);
            acc[1][j] = __builtin_amdgcn_mfma_f32_16x16x32_bf16(a1, ring[f], acc[1][j], 0, 0, 0);
            ring[f] = gload(Wb5 + w5off(0));   // keep depth constant (dummy)
        }
        drain16(ring);

        float* __restrict__ p = (float*)&lds[OFF_P];
        #pragma unroll
        for (int j = 0; j < 4; ++j) {
            const int col = wn * 64 + j * 16 + m_l;
            #pragma unroll
            for (int i = 0; i < 2; ++i)
                #pragma unroll
                for (int r = 0; r < 4; ++r)
                    p[(mrow + i*16 + quad*4 + r) * LD_P + col] = acc[i][j][r];
        }
    }
    __syncthreads();

    // ---- QP: one row per wave-iteration, contiguous float4 LDS reads -------
    const float b0 = bnd.x, b1 = bnd.y, b2 = bnd.z, b3 = bnd.w;
    const float* __restrict__ p = (const float*)&lds[OFF_P];
    #pragma unroll
    for (int i = 0; i < 8; ++i) {
        const int row = i * 8 + wid;                 // 0..63, uniform per wave
        const float4 pv = *(const float4*)&p[row * LD_P + lane * 4];
        float xs, wo, ys, ho;
        {
            const float px = pv.x, pw = pv.z;
            const float x0 = fmaxf(px, b0);
            const float g0 = fmaxf(pw, 1.0f);
            const float t  = 0.5f * (b2 - px - pw);
            const float xl = fminf(fmaxf(px + t, b0), b2 - 1.0f);
            const bool over = (x0 + g0) > b2;
            const float x = over ? xl : x0;
            const float g = over ? (b2 - xl) : g0;
            xs = x; wo = x + g;
        }
        {
            const float py = pv.y, ph = pv.w;
            const float x0 = fmaxf(py, b1);
            const float g0 = fmaxf(ph, 1.0f);
            const float t  = 0.5f * (b3 - py - ph);
            const float xl = fminf(fmaxf(py + t, b1), b3 - 1.0f);
            const bool over = (x0 + g0) > b3;
            const float x = over ? xl : x0;
            const float g = over ? (b3 - xl) : g0;
            ys = x; ho = x + g;
        }
        float4 o; o.x = xs; o.y = ys; o.z = wo; o.w = ho;
        ((float4*)out)[(size_t)(bm + row) * 64 + lane] = o;
    }
}

extern "C" void kernel_launch(void* const* d_in, const int* in_sizes, int n_in,
                              void* d_out, int out_size, void* d_ws, size_t ws_size,
                              hipStream_t stream) {
    const float* z      = (const float*)d_in[0];
    const float* bounds = (const float*)d_in[1];
    const float* W1 = (const float*)d_in[2];
    const float* c1 = (const float*)d_in[3];
    const float* W2 = (const float*)d_in[4];
    const float* c2 = (const float*)d_in[5];
    const float* W3 = (const float*)d_in[6];
    const float* c3 = (const float*)d_in[7];
    const float* W4 = (const float*)d_in[8];
    const float* c4 = (const float*)d_in[9];
    const float* W5 = (const float*)d_in[10];
    const float* c5 = (const float*)d_in[11];
    float* out = (float*)d_out;

    unsigned short* ws  = (unsigned short*)d_ws;
    unsigned short* Wt1 = ws;               // 512x544 = 278528
    unsigned short* Wt2 = Wt1 + 278528;     // 256x512 = 131072
    unsigned short* Wt3 = Wt2 + 131072;     // 128x256 = 32768
    unsigned short* Wt4 = Wt3 + 32768;      //  64x128 =  8192
    unsigned short* Wt5 = Wt4 + 8192;       // 256x64x2 = 32768 (hi/lo)

    pack_wt<<<dim3(1088, 5), 256, 0, stream>>>(
        W1, Wt1, W2, Wt2, W3, Wt3, W4, Wt4, W5, Wt5);
    fused_mlp_qp<<<dim3(MROWS / 64), 512, 0, stream>>>(
        z, bounds, Wt1, c1, Wt2, c2, Wt3, c3, Wt4, c4, Wt5, c5, out);
}